// Round 6
// baseline (994.971 us; speedup 1.0000x reference)
//
#include <hip/hip_runtime.h>

// Problem constants (fixed by the reference):
#define T_DATA 100000
#define E_NO   1000
#define SUB    20
#define TSYN   201

// ===========================================================================
// K1: syn[t][s] = sum_e S[t][e] * C[s][e]
// v2 after rocprof post-mortem: v1's scalar-path C loads (20 s_load/iter/wave)
// saturated the per-CU scalar pipe (measured: 1200cyc/iter, VALUBusy 15%).
// Now: C staged in LDS once per block (78KB), read as broadcast ds_read_b128;
// R=2 rows/lane amortizes each C read over 8 FMAs (LDS return-path budget
// 5.1k cyc < 6.3k cyc HBM-paced round per CU). S read in 64B/lane steps
// (full line consumed immediately -> no L1 reuse window needed) and
// prefetched one step ahead (8KB/wave in flight).
// Block 256 thr = 4 waves; each wave owns one 128-row strip (lane l -> rows
// strip*128+l, +64). Grid (196,2): 784 strips/side >= 782 needed; 2 blocks/CU.
// ===========================================================================
__global__ __launch_bounds__(256) void k1_matmul(
    const float* __restrict__ S_e, const float* __restrict__ S_i,
    const float* __restrict__ C_e, const float* __restrict__ C_i,
    float* __restrict__ sy_e, float* __restrict__ sy_i)
{
    __shared__ float4 CT[250 * SUB];     // C transposed: CT[j][s], 78.1 KiB
    const int tid = threadIdx.x;
    const float* __restrict__ Sp = blockIdx.y ? S_i : S_e;
    const float* __restrict__ Cp = blockIdx.y ? C_i : C_e;
    float* __restrict__ outp = blockIdx.y ? sy_i : sy_e;

    // ---- stage C: global [s][250 float4] -> LDS CT[j][s] ----
    {
        const float4* __restrict__ C4 = reinterpret_cast<const float4*>(Cp);
        for (int i = tid; i < 250 * SUB; i += 256) {
            const int s = i / 250, j = i - s * 250;   // coalesced global read
            CT[j * SUB + s] = C4[i];
        }
    }
    __syncthreads();

    const int lane  = tid & 63;
    const int wv    = tid >> 6;
    const int strip = blockIdx.x * 4 + wv;            // 0..783 (782,783 idle)
    const int r0 = strip * 128 + lane;
    const int r1 = r0 + 64;
    const int cr0 = r0 < T_DATA ? r0 : T_DATA - 1;    // clamp: loads harmless
    const int cr1 = r1 < T_DATA ? r1 : T_DATA - 1;

    const float4* __restrict__ p0 = reinterpret_cast<const float4*>(Sp + (size_t)cr0 * E_NO);
    const float4* __restrict__ p1 = reinterpret_cast<const float4*>(Sp + (size_t)cr1 * E_NO);

    float acc0[SUB], acc1[SUB];
#pragma unroll
    for (int s = 0; s < SUB; ++s) { acc0[s] = 0.f; acc1[s] = 0.f; }

    // current / next 64B step buffers (4 float4 per row)
    float4 ca[4], cb[4];
#pragma unroll
    for (int k = 0; k < 4; ++k) { ca[k] = p0[k]; cb[k] = p1[k]; }

    for (int jb = 0; jb < 62; ++jb) {                 // steps of 4 chunks (16 floats)
        float4 na[4], nb[4];
        const int nbase = 4 * jb + 4;
#pragma unroll
        for (int k = 0; k < 4; ++k) {                 // prefetch next step
            const int idx = (nbase + k < 250) ? nbase + k : 249;
            na[k] = p0[idx]; nb[k] = p1[idx];
        }
#pragma unroll
        for (int k = 0; k < 4; ++k) {
            const float4* __restrict__ crow = &CT[(4 * jb + k) * SUB];
            const float4 av = ca[k], bv = cb[k];
#pragma unroll
            for (int s = 0; s < SUB; ++s) {
                const float4 c4 = crow[s];            // broadcast (uniform addr)
                acc0[s] = fmaf(av.x, c4.x, acc0[s]);
                acc0[s] = fmaf(av.y, c4.y, acc0[s]);
                acc0[s] = fmaf(av.z, c4.z, acc0[s]);
                acc0[s] = fmaf(av.w, c4.w, acc0[s]);
                acc1[s] = fmaf(bv.x, c4.x, acc1[s]);
                acc1[s] = fmaf(bv.y, c4.y, acc1[s]);
                acc1[s] = fmaf(bv.z, c4.z, acc1[s]);
                acc1[s] = fmaf(bv.w, c4.w, acc1[s]);
            }
        }
#pragma unroll
        for (int k = 0; k < 4; ++k) { ca[k] = na[k]; cb[k] = nb[k]; }
    }
    // tail: chunks 248, 249 live in ca[0], ca[1] (clamped prefetch)
#pragma unroll
    for (int k = 0; k < 2; ++k) {
        const float4* __restrict__ crow = &CT[(248 + k) * SUB];
        const float4 av = ca[k], bv = cb[k];
#pragma unroll
        for (int s = 0; s < SUB; ++s) {
            const float4 c4 = crow[s];
            acc0[s] = fmaf(av.x, c4.x, acc0[s]);
            acc0[s] = fmaf(av.y, c4.y, acc0[s]);
            acc0[s] = fmaf(av.z, c4.z, acc0[s]);
            acc0[s] = fmaf(av.w, c4.w, acc0[s]);
            acc1[s] = fmaf(bv.x, c4.x, acc1[s]);
            acc1[s] = fmaf(bv.y, c4.y, acc1[s]);
            acc1[s] = fmaf(bv.z, c4.z, acc1[s]);
            acc1[s] = fmaf(bv.w, c4.w, acc1[s]);
        }
    }

    if (r0 < T_DATA) {
        float* op = outp + (size_t)r0 * SUB;
#pragma unroll
        for (int c = 0; c < 5; ++c)
            *reinterpret_cast<float4*>(op + 4 * c) =
                make_float4(acc0[4*c], acc0[4*c+1], acc0[4*c+2], acc0[4*c+3]);
    }
    if (r1 < T_DATA) {
        float* op = outp + (size_t)r1 * SUB;
#pragma unroll
        for (int c = 0; c < 5; ++c)
            *reinterpret_cast<float4*>(op + 4 * c) =
                make_float4(acc1[4*c], acc1[4*c+1], acc1[4*c+2], acc1[4*c+3]);
    }
}

// ===========================================================================
// K2 (fused conv + dendritic epilogue), rebalanced for occupancy:
// 128-output tiles (328 staged rows), LDS 59KB -> 2 blocks/CU, 782 blocks.
// 5 waves; wave g owns s-group {4g..4g+3}; lanes = 16 t x 4 s; each thread
// 8 consecutive outputs via sliding window W0[8]/W1[8] (1 LDS read/k-step).
// Swizzle u+(u>>3): lane t_l stride 9 words -> 16 distinct banks.
// ===========================================================================
#define KROWS 328      // 200 halo + 128
#define P2    369      // pitch: max swz(327)=367; odd

__global__ __launch_bounds__(320) void k2_conv_epi(
    const float* __restrict__ sy_e, const float* __restrict__ sy_i,
    const float* __restrict__ w_e, const float* __restrict__ b_e,
    const float* __restrict__ w_i, const float* __restrict__ b_i,
    const float* __restrict__ Cden, const float* __restrict__ Wss,
    float* __restrict__ dout)
{
    __shared__ float A0[SUB * P2];   // syn_e tile (29.5 KB)
    __shared__ float A1[SUB * P2];   // syn_i tile
    const int tid = threadIdx.x;
    const int tb  = blockIdx.x * 128;

    // ---- stage: 328 rows x 5 float4 x {e,i} = 3280 loads ----
    for (int m = 0; m < 11; ++m) {
        int idx = tid + 320 * m;
        if (idx >= 3280) break;
        int a   = idx >= 1640;
        int id2 = idx - a * 1640;
        int u   = id2 / 5;
        int c   = id2 - 5 * u;
        int t   = tb - 200 + u;
        float4 v = make_float4(0.f, 0.f, 0.f, 0.f);
        const float* src = a ? sy_i : sy_e;
        if (t >= 0 && t < T_DATA) v = *reinterpret_cast<const float4*>(src + t * SUB + 4 * c);
        float* dst = a ? A1 : A0;
        const int sw = u + (u >> 3);                  // max 367 < 369
        dst[(4 * c + 0) * P2 + sw] = v.x;
        dst[(4 * c + 1) * P2 + sw] = v.y;
        dst[(4 * c + 2) * P2 + sw] = v.z;
        dst[(4 * c + 3) * P2 + sw] = v.w;
    }
    __syncthreads();

    const int lane = tid & 63;
    const int g    = tid >> 6;
    const int t_l  = lane & 15;
    const int s_l  = lane >> 4;
    const int s    = 4 * g + s_l;

    float out[8];
    const float bias = b_e[s] + b_i[s];
#pragma unroll
    for (int i = 0; i < 8; ++i) out[i] = bias;

    const int rb = s * P2 + 9 * t_l;                  // swz(8*t_l) = 9*t_l

#pragma unroll 1
    for (int cv = 0; cv < 2; ++cv) {
        const float* Ap = cv ? A1 : A0;
        const float* wp = (cv ? w_i : w_e) + s * TSYN;
        float W0[8], W1[8];
#pragma unroll
        for (int j = 0; j < 8; ++j) W0[j] = Ap[rb + j];         // swz contiguous
#pragma unroll
        for (int j = 0; j < 8; ++j) W1[j] = Ap[rb + 9 + j];     // u0+8: +9 swz
#pragma unroll 1
        for (int c = 0; c < 25; ++c) {                // k = 8c..8c+7
            float wr[8];
#pragma unroll
            for (int kk = 0; kk < 8; ++kk) wr[kk] = wp[8 * c + kk];
#pragma unroll
            for (int kk = 0; kk < 8; ++kk) {
                const float wv = wr[kk];
#pragma unroll
                for (int i = 0; i < 8; ++i) {
                    const int ix = kk + i;            // 0..14, static
                    const float av = (ix < 8) ? W0[ix] : W1[ix - 8];
                    out[i] = fmaf(wv, av, out[i]);
                }
            }
#pragma unroll
            for (int j = 0; j < 8; ++j) W0[j] = W1[j];
            if (c < 24) {                             // last refill would read u>327
                const int co = 8 * c + 16;            // co % 8 == 0
                const int cb = rb + co + (co >> 3);
#pragma unroll
                for (int j = 0; j < 8; ++j) W1[j] = Ap[cb + j];
            }
        }
        { // tail k = 200: W0 now = A[u = 8t_l+200 .. +207]
            const float wlast = wp[200];
#pragma unroll
            for (int i = 0; i < 8; ++i) out[i] = fmaf(wlast, W0[i], out[i]);
        }
    }

    // ---- epilogue: exchange synin through LDS (reuse A0) ----
    __syncthreads();                                  // conv reads of A0/A1 done
    float* Yt = A0;                                   // [128][21] = 2688 floats
#pragma unroll
    for (int i = 0; i < 8; ++i) Yt[(8 * t_l + i) * 21 + s] = out[i];
    __syncthreads();

    if (tid < 128) {
        const int t = tb + tid;
        if (t < T_DATA) {
            float* __restrict__ volt = dout;
            float* __restrict__ Y1 = dout + T_DATA;
            float* __restrict__ Y2 = dout + T_DATA + (size_t)T_DATA * SUB;
            float row[SUB], uu[SUB];
#pragma unroll
            for (int sp = 0; sp < SUB; ++sp) {
                const float r = Yt[tid * 21 + sp];    // stride 21: conflict-free
                row[sp] = r;
                uu[sp]  = r * expf(Wss[sp]);          // uniform -> s_load
            }
            float y[SUB];
#pragma unroll
            for (int s2 = 0; s2 < SUB; ++s2) {
                float a2 = row[s2];
#pragma unroll
                for (int sp = 0; sp < SUB; ++sp)
                    a2 = fmaf(Cden[s2 * SUB + sp], uu[sp], a2);
                y[s2] = a2;
            }
            float* o1 = Y1 + (size_t)t * SUB;
            float* o2 = Y2 + (size_t)t * SUB;
#pragma unroll
            for (int c = 0; c < 5; ++c) {
                float4 v = make_float4(y[4*c], y[4*c+1], y[4*c+2], y[4*c+3]);
                *reinterpret_cast<float4*>(o1 + 4 * c) = v;
                *reinterpret_cast<float4*>(o2 + 4 * c) = v;
            }
            volt[t] = y[0] * expf(Wss[0]);
        }
    }
}

// ---------------------------------------------------------------------------
extern "C" void kernel_launch(void* const* d_in, const int* in_sizes, int n_in,
                              void* d_out, int out_size, void* d_ws, size_t ws_size,
                              hipStream_t stream)
{
    const float* S_e  = (const float*)d_in[0];
    const float* S_i  = (const float*)d_in[1];
    const float* C_e  = (const float*)d_in[2];
    const float* C_i  = (const float*)d_in[3];
    const float* Cden = (const float*)d_in[4];
    const float* w_e  = (const float*)d_in[5];
    const float* b_e  = (const float*)d_in[6];
    const float* w_i  = (const float*)d_in[7];
    const float* b_i  = (const float*)d_in[8];
    const float* Wss  = (const float*)d_in[9];
    float* out  = (float*)d_out;
    float* sy_e = (float*)d_ws;                      // [T][20] fp32, 8 MB
    float* sy_i = sy_e + (size_t)T_DATA * SUB;       // 8 MB

    // K1: grid (196,2); 4 strips/block x 128 rows = 512 rows/block
    dim3 g1(196, 2);
    k1_matmul<<<g1, 256, 0, stream>>>(S_e, S_i, C_e, C_i, sy_e, sy_i);
    // K2: 128-output tiles, fused conv + dendritic hop + voltage
    k2_conv_epi<<<782, 320, 0, stream>>>(sy_e, sy_i, w_e, b_e, w_i, b_i,
                                         Cden, Wss, out);
}